// Round 3
// baseline (202.356 us; speedup 1.0000x reference)
//
#include <hip/hip_runtime.h>
#include <math.h>

#define EXTRA_COE 0.5f
#define ROWS_PER_BLOCK 4   // 4 waves of 64, one wave per row

typedef __attribute__((ext_vector_type(4))) float f32x4;

// D=1024: one wave per row; lane i owns float4s {i, i+64, i+128, i+192} of
// each stream. All 12 global_load_dwordx4 are FORCED in flight via inline
// asm (single s_waitcnt vmcnt(0)) -- R2 showed the compiler regroups source-
// level batched loads into ~4-in-flight (VGPR_Count=32), leaving the kernel
// latency-serialized at 2.8 TB/s effective.
__global__ __launch_bounds__(256) void st_loss_rows_1024(
    const float* __restrict__ ea, const float* __restrict__ ep,
    const float* __restrict__ en, const float* __restrict__ td,
    const int* __restrict__ bidx, float* __restrict__ partial, int B)
{
    const int wave = threadIdx.x >> 6;
    const int lane = threadIdx.x & 63;
    const int row  = blockIdx.x * ROWS_PER_BLOCK + wave;

    float row_loss = 0.0f;
    if (row < B) {
        const size_t off = (size_t)row * 1024u + (size_t)lane * 4u;
        const float* pa = ea + off;
        const float* pp = ep + off;
        const float* pn = en + off;

        f32x4 a0, a1, a2, a3, p0, p1, p2, p3, q0, q1, q2, q3;
        asm volatile(
            "global_load_dwordx4 %[a0], %[pa], off\n\t"
            "global_load_dwordx4 %[a1], %[pa], off offset:1024\n\t"
            "global_load_dwordx4 %[a2], %[pa], off offset:2048\n\t"
            "global_load_dwordx4 %[a3], %[pa], off offset:3072\n\t"
            "global_load_dwordx4 %[p0], %[pp], off\n\t"
            "global_load_dwordx4 %[p1], %[pp], off offset:1024\n\t"
            "global_load_dwordx4 %[p2], %[pp], off offset:2048\n\t"
            "global_load_dwordx4 %[p3], %[pp], off offset:3072\n\t"
            "global_load_dwordx4 %[q0], %[pn], off\n\t"
            "global_load_dwordx4 %[q1], %[pn], off offset:1024\n\t"
            "global_load_dwordx4 %[q2], %[pn], off offset:2048\n\t"
            "global_load_dwordx4 %[q3], %[pn], off offset:3072\n\t"
            "s_waitcnt vmcnt(0)"
            : [a0]"=&v"(a0), [a1]"=&v"(a1), [a2]"=&v"(a2), [a3]"=&v"(a3),
              [p0]"=&v"(p0), [p1]"=&v"(p1), [p2]"=&v"(p2), [p3]"=&v"(p3),
              [q0]"=&v"(q0), [q1]"=&v"(q1), [q2]"=&v"(q2), [q3]"=&v"(q3)
            : [pa]"v"(pa), [pp]"v"(pp), [pn]"v"(pn)
            : "memory");

        float s_ap = 0.0f, s_an = 0.0f;
        {
            f32x4 d;
            d = a0 - p0; s_ap += d.x*d.x + d.y*d.y + d.z*d.z + d.w*d.w;
            d = a1 - p1; s_ap += d.x*d.x + d.y*d.y + d.z*d.z + d.w*d.w;
            d = a2 - p2; s_ap += d.x*d.x + d.y*d.y + d.z*d.z + d.w*d.w;
            d = a3 - p3; s_ap += d.x*d.x + d.y*d.y + d.z*d.z + d.w*d.w;
            d = a0 - q0; s_an += d.x*d.x + d.y*d.y + d.z*d.z + d.w*d.w;
            d = a1 - q1; s_an += d.x*d.x + d.y*d.y + d.z*d.z + d.w*d.w;
            d = a2 - q2; s_an += d.x*d.x + d.y*d.y + d.z*d.z + d.w*d.w;
            d = a3 - q3; s_an += d.x*d.x + d.y*d.y + d.z*d.z + d.w*d.w;
        }

        #pragma unroll
        for (int offx = 32; offx >= 1; offx >>= 1) {
            s_ap += __shfl_xor(s_ap, offx, 64);
            s_an += __shfl_xor(s_an, offx, 64);
        }
        if (lane == 0) {
            const float v_ap = expf(-sqrtf(s_ap));
            const float v_an = expf(-sqrtf(s_an));
            const int idx = bidx[row];
            const float d0 = td[2 * idx + 0] * EXTRA_COE;
            const float d1 = td[2 * idx + 1] * EXTRA_COE;
            const float D_ap = expf(-d0);
            const float D_an = expf(-d1);
            float l = (D_ap - v_ap) * (D_ap - v_ap)
                    + (D_an - v_an) * (D_an - v_an);
            if (D_ap > D_an) {
                float m = v_an - v_ap;
                m = m > 0.0f ? m : 0.0f;
                l += m * m;
            }
            row_loss = l;
        }
    }

    __shared__ float sm[ROWS_PER_BLOCK];
    if (lane == 0) sm[wave] = row_loss;
    __syncthreads();
    if (threadIdx.x == 0) {
        float s = 0.0f;
        #pragma unroll
        for (int w = 0; w < ROWS_PER_BLOCK; ++w) s += sm[w];
        partial[blockIdx.x] = s;
    }
}

// Generic-D fallback.
__global__ __launch_bounds__(256) void st_loss_rows_gen(
    const float* __restrict__ ea, const float* __restrict__ ep,
    const float* __restrict__ en, const float* __restrict__ td,
    const int* __restrict__ bidx, float* __restrict__ partial,
    int B, int D)
{
    const int wave = threadIdx.x >> 6;
    const int lane = threadIdx.x & 63;
    const int row  = blockIdx.x * ROWS_PER_BLOCK + wave;

    float row_loss = 0.0f;
    if (row < B) {
        const size_t base = (size_t)row * (size_t)D;
        const float4* a4 = (const float4*)(ea + base);
        const float4* p4 = (const float4*)(ep + base);
        const float4* n4 = (const float4*)(en + base);
        const int nvec = D >> 2;

        float s_ap = 0.0f, s_an = 0.0f;
        for (int j = lane; j < nvec; j += 64) {
            float4 av = a4[j], pv = p4[j], nv = n4[j];
            float dx = av.x - pv.x, dy = av.y - pv.y,
                  dz = av.z - pv.z, dw = av.w - pv.w;
            s_ap += dx*dx + dy*dy + dz*dz + dw*dw;
            dx = av.x - nv.x; dy = av.y - nv.y;
            dz = av.z - nv.z; dw = av.w - nv.w;
            s_an += dx*dx + dy*dy + dz*dz + dw*dw;
        }
        #pragma unroll
        for (int offx = 32; offx >= 1; offx >>= 1) {
            s_ap += __shfl_xor(s_ap, offx, 64);
            s_an += __shfl_xor(s_an, offx, 64);
        }
        if (lane == 0) {
            const float v_ap = expf(-sqrtf(s_ap));
            const float v_an = expf(-sqrtf(s_an));
            const int idx = bidx[row];
            const float d0 = td[2 * idx + 0] * EXTRA_COE;
            const float d1 = td[2 * idx + 1] * EXTRA_COE;
            const float D_ap = expf(-d0);
            const float D_an = expf(-d1);
            float l = (D_ap - v_ap) * (D_ap - v_ap)
                    + (D_an - v_an) * (D_an - v_an);
            if (D_ap > D_an) {
                float m = v_an - v_ap;
                m = m > 0.0f ? m : 0.0f;
                l += m * m;
            }
            row_loss = l;
        }
    }

    __shared__ float sm[ROWS_PER_BLOCK];
    if (lane == 0) sm[wave] = row_loss;
    __syncthreads();
    if (threadIdx.x == 0) {
        float s = 0.0f;
        #pragma unroll
        for (int w = 0; w < ROWS_PER_BLOCK; ++w) s += sm[w];
        partial[blockIdx.x] = s;
    }
}

__global__ __launch_bounds__(256) void st_loss_final(
    const float* __restrict__ partial, int n_partial,
    float* __restrict__ out, float inv_b)
{
    float s = 0.0f;
    for (int i = threadIdx.x; i < n_partial; i += 256) s += partial[i];
    #pragma unroll
    for (int offx = 32; offx >= 1; offx >>= 1) s += __shfl_xor(s, offx, 64);
    __shared__ float sm[4];
    if ((threadIdx.x & 63) == 0) sm[threadIdx.x >> 6] = s;
    __syncthreads();
    if (threadIdx.x == 0) out[0] = (sm[0] + sm[1] + sm[2] + sm[3]) * inv_b;
}

extern "C" void kernel_launch(void* const* d_in, const int* in_sizes, int n_in,
                              void* d_out, int out_size, void* d_ws, size_t ws_size,
                              hipStream_t stream) {
    const float* ea   = (const float*)d_in[0];
    const float* ep   = (const float*)d_in[1];
    const float* en   = (const float*)d_in[2];
    const float* td   = (const float*)d_in[3];
    const int*   bidx = (const int*)d_in[4];
    float* out = (float*)d_out;

    const int B = in_sizes[4];                 // 16384 rows
    const int D = in_sizes[0] / B;             // 1024
    const int n_blocks = (B + ROWS_PER_BLOCK - 1) / ROWS_PER_BLOCK;

    float* partial = (float*)d_ws;             // n_blocks floats

    if (D == 1024) {
        st_loss_rows_1024<<<n_blocks, 256, 0, stream>>>(ea, ep, en, td, bidx,
                                                        partial, B);
    } else {
        st_loss_rows_gen<<<n_blocks, 256, 0, stream>>>(ea, ep, en, td, bidx,
                                                       partial, B, D);
    }
    st_loss_final<<<1, 256, 0, stream>>>(partial, n_blocks, out, 1.0f / (float)B);
}

// Round 4
// 183.550 us; speedup vs baseline: 1.1025x; 1.1025x over previous
//
#include <hip/hip_runtime.h>
#include <math.h>

#define EXTRA_COE 0.5f
#define ROWS_PER_BLOCK 4   // 4 waves of 64, one wave per row

typedef __attribute__((ext_vector_type(4))) float f32x4;

// R4: nontemporal streaming loads. R1-R3 showed a structure-insensitive
// 2.8 TB/s read ceiling, identical whether data comes from L3 or HBM ->
// bottleneck is the L2-miss/allocation path. Streaming data has zero reuse,
// so bypass L2 allocation entirely (global_load_dwordx4 ... nt) to remove
// line-fill + dirty-eviction overhead from the fabric path.
__global__ __launch_bounds__(256) void st_loss_rows_1024(
    const float* __restrict__ ea, const float* __restrict__ ep,
    const float* __restrict__ en, const float* __restrict__ td,
    const int* __restrict__ bidx, float* __restrict__ partial, int B)
{
    const int wave = threadIdx.x >> 6;
    const int lane = threadIdx.x & 63;
    const int row  = blockIdx.x * ROWS_PER_BLOCK + wave;

    float row_loss = 0.0f;
    if (row < B) {
        const size_t base = (size_t)row * 1024u;
        const f32x4* a4 = (const f32x4*)(ea + base);
        const f32x4* p4 = (const f32x4*)(ep + base);
        const f32x4* n4 = (const f32x4*)(en + base);

        f32x4 av[4], pv[4], nv[4];
        #pragma unroll
        for (int k = 0; k < 4; ++k) av[k] = __builtin_nontemporal_load(&a4[lane + 64 * k]);
        #pragma unroll
        for (int k = 0; k < 4; ++k) pv[k] = __builtin_nontemporal_load(&p4[lane + 64 * k]);
        #pragma unroll
        for (int k = 0; k < 4; ++k) nv[k] = __builtin_nontemporal_load(&n4[lane + 64 * k]);

        float s_ap = 0.0f, s_an = 0.0f;
        #pragma unroll
        for (int k = 0; k < 4; ++k) {
            f32x4 d = av[k] - pv[k];
            s_ap += d.x*d.x + d.y*d.y + d.z*d.z + d.w*d.w;
            d = av[k] - nv[k];
            s_an += d.x*d.x + d.y*d.y + d.z*d.z + d.w*d.w;
        }

        #pragma unroll
        for (int offx = 32; offx >= 1; offx >>= 1) {
            s_ap += __shfl_xor(s_ap, offx, 64);
            s_an += __shfl_xor(s_an, offx, 64);
        }
        if (lane == 0) {
            const float v_ap = expf(-sqrtf(s_ap));
            const float v_an = expf(-sqrtf(s_an));
            const int idx = bidx[row];
            const float d0 = td[2 * idx + 0] * EXTRA_COE;
            const float d1 = td[2 * idx + 1] * EXTRA_COE;
            const float D_ap = expf(-d0);
            const float D_an = expf(-d1);
            float l = (D_ap - v_ap) * (D_ap - v_ap)
                    + (D_an - v_an) * (D_an - v_an);
            if (D_ap > D_an) {
                float m = v_an - v_ap;
                m = m > 0.0f ? m : 0.0f;
                l += m * m;
            }
            row_loss = l;
        }
    }

    __shared__ float sm[ROWS_PER_BLOCK];
    if (lane == 0) sm[wave] = row_loss;
    __syncthreads();
    if (threadIdx.x == 0) {
        float s = 0.0f;
        #pragma unroll
        for (int w = 0; w < ROWS_PER_BLOCK; ++w) s += sm[w];
        partial[blockIdx.x] = s;
    }
}

// Generic-D fallback (nt loads as well).
__global__ __launch_bounds__(256) void st_loss_rows_gen(
    const float* __restrict__ ea, const float* __restrict__ ep,
    const float* __restrict__ en, const float* __restrict__ td,
    const int* __restrict__ bidx, float* __restrict__ partial,
    int B, int D)
{
    const int wave = threadIdx.x >> 6;
    const int lane = threadIdx.x & 63;
    const int row  = blockIdx.x * ROWS_PER_BLOCK + wave;

    float row_loss = 0.0f;
    if (row < B) {
        const size_t base = (size_t)row * (size_t)D;
        const f32x4* a4 = (const f32x4*)(ea + base);
        const f32x4* p4 = (const f32x4*)(ep + base);
        const f32x4* n4 = (const f32x4*)(en + base);
        const int nvec = D >> 2;

        float s_ap = 0.0f, s_an = 0.0f;
        for (int j = lane; j < nvec; j += 64) {
            f32x4 av = __builtin_nontemporal_load(&a4[j]);
            f32x4 pv = __builtin_nontemporal_load(&p4[j]);
            f32x4 nv = __builtin_nontemporal_load(&n4[j]);
            f32x4 d = av - pv;
            s_ap += d.x*d.x + d.y*d.y + d.z*d.z + d.w*d.w;
            d = av - nv;
            s_an += d.x*d.x + d.y*d.y + d.z*d.z + d.w*d.w;
        }
        #pragma unroll
        for (int offx = 32; offx >= 1; offx >>= 1) {
            s_ap += __shfl_xor(s_ap, offx, 64);
            s_an += __shfl_xor(s_an, offx, 64);
        }
        if (lane == 0) {
            const float v_ap = expf(-sqrtf(s_ap));
            const float v_an = expf(-sqrtf(s_an));
            const int idx = bidx[row];
            const float d0 = td[2 * idx + 0] * EXTRA_COE;
            const float d1 = td[2 * idx + 1] * EXTRA_COE;
            const float D_ap = expf(-d0);
            const float D_an = expf(-d1);
            float l = (D_ap - v_ap) * (D_ap - v_ap)
                    + (D_an - v_an) * (D_an - v_an);
            if (D_ap > D_an) {
                float m = v_an - v_ap;
                m = m > 0.0f ? m : 0.0f;
                l += m * m;
            }
            row_loss = l;
        }
    }

    __shared__ float sm[ROWS_PER_BLOCK];
    if (lane == 0) sm[wave] = row_loss;
    __syncthreads();
    if (threadIdx.x == 0) {
        float s = 0.0f;
        #pragma unroll
        for (int w = 0; w < ROWS_PER_BLOCK; ++w) s += sm[w];
        partial[blockIdx.x] = s;
    }
}

__global__ __launch_bounds__(256) void st_loss_final(
    const float* __restrict__ partial, int n_partial,
    float* __restrict__ out, float inv_b)
{
    float s = 0.0f;
    for (int i = threadIdx.x; i < n_partial; i += 256) s += partial[i];
    #pragma unroll
    for (int offx = 32; offx >= 1; offx >>= 1) s += __shfl_xor(s, offx, 64);
    __shared__ float sm[4];
    if ((threadIdx.x & 63) == 0) sm[threadIdx.x >> 6] = s;
    __syncthreads();
    if (threadIdx.x == 0) out[0] = (sm[0] + sm[1] + sm[2] + sm[3]) * inv_b;
}

extern "C" void kernel_launch(void* const* d_in, const int* in_sizes, int n_in,
                              void* d_out, int out_size, void* d_ws, size_t ws_size,
                              hipStream_t stream) {
    const float* ea   = (const float*)d_in[0];
    const float* ep   = (const float*)d_in[1];
    const float* en   = (const float*)d_in[2];
    const float* td   = (const float*)d_in[3];
    const int*   bidx = (const int*)d_in[4];
    float* out = (float*)d_out;

    const int B = in_sizes[4];                 // 16384 rows
    const int D = in_sizes[0] / B;             // 1024
    const int n_blocks = (B + ROWS_PER_BLOCK - 1) / ROWS_PER_BLOCK;

    float* partial = (float*)d_ws;             // n_blocks floats

    if (D == 1024) {
        st_loss_rows_1024<<<n_blocks, 256, 0, stream>>>(ea, ep, en, td, bidx,
                                                        partial, B);
    } else {
        st_loss_rows_gen<<<n_blocks, 256, 0, stream>>>(ea, ep, en, td, bidx,
                                                       partial, B, D);
    }
    st_loss_final<<<1, 256, 0, stream>>>(partial, n_blocks, out, 1.0f / (float)B);
}